// Round 6
// baseline (1725.175 us; speedup 1.0000x reference)
//
#include <hip/hip_runtime.h>

// ==================== utility ====================
__global__ void k_zero_i(int* __restrict__ p, int n) {
    int i = blockIdx.x * blockDim.x + threadIdx.x;
    if (i < n) p[i] = 0;
}
__global__ void k_zero_f(float* __restrict__ p, long n) {
    long i = blockIdx.x * (long)blockDim.x + threadIdx.x;
    if (i < n) p[i] = 0.0f;
}

// ==================== bucketed CSR build ====================
// NB = 64 nodes per bucket; bucket id = col >> 6.
__global__ void k_bcount(const int* __restrict__ col, int* __restrict__ bcnt, int e) {
    int i = blockIdx.x * blockDim.x + threadIdx.x;
    if (i < e) atomicAdd(&bcnt[col[i] >> 6], 1);
}

// single-block exclusive scan of B bucket counts (B <= 4096)
__global__ void k_bscan(const int* __restrict__ bcnt, int* __restrict__ bstart,
                        int* __restrict__ bcur, int B) {
    __shared__ int ts[1024];
    const int tid = threadIdx.x;
    const int chunk = (B + 1023) >> 10;   // <= 4
    const int base = tid * chunk;
    int v[4] = {0, 0, 0, 0};
    int sum = 0;
    #pragma unroll
    for (int k = 0; k < 4; ++k) {
        if (k < chunk) {
            int idx = base + k;
            int t = (idx < B) ? bcnt[idx] : 0;
            v[k] = t; sum += t;
        }
    }
    ts[tid] = sum;
    __syncthreads();
    for (int off = 1; off < 1024; off <<= 1) {
        int add = (tid >= off) ? ts[tid - off] : 0;
        __syncthreads();
        ts[tid] += add;
        __syncthreads();
    }
    int excl = ts[tid] - sum;
    #pragma unroll
    for (int k = 0; k < 4; ++k) {
        if (k < chunk) {
            int idx = base + k;
            if (idx < B) { bstart[idx] = excl; bcur[idx] = excl; excl += v[k]; }
        }
    }
    if (tid == 1023) bstart[B] = ts[1023];
}

// partition edges into bucket regions; ONE 8B write per edge at the bucket frontier
// (concurrent cursor positions are adjacent -> lines fully populated -> write ~= payload)
__global__ void k_partition(const int* __restrict__ row, const int* __restrict__ col,
                            int* __restrict__ bcur, int2* __restrict__ eb, int e) {
    int i = blockIdx.x * blockDim.x + threadIdx.x;
    if (i >= e) return;
    int c = col[i];
    int p = atomicAdd(&bcur[c >> 6], 1);
    eb[p] = make_int2(row[i], ((c & 63) << 26) | i);   // eid < 2^26 guaranteed by caller
}

// one block per bucket: per-node counts + scan in LDS, emit startp/dinv,
// then scatter srow/seid WITHIN the bucket's small L2-resident region.
__global__ void k_bucket_csr(const int2* __restrict__ eb, const int* __restrict__ bstart,
                             int* __restrict__ srow, int* __restrict__ seid,
                             int* __restrict__ startp, float* __restrict__ dinv,
                             int n, int e) {
    __shared__ int scnt[64];
    __shared__ int sexcl[64];
    const int b = blockIdx.x;
    const int tid = threadIdx.x;
    if (tid < 64) scnt[tid] = 0;
    __syncthreads();
    const int s = bstart[b], s1 = bstart[b + 1];
    for (int i = s + tid; i < s1; i += 256) {
        int cl = (eb[i].y >> 26) & 63;
        atomicAdd(&scnt[cl], 1);
    }
    __syncthreads();
    if (tid < 64) {   // wave 0: inclusive scan of 64 counters
        int v = scnt[tid];
        int acc = v;
        #pragma unroll
        for (int off = 1; off < 64; off <<= 1) {
            int t = __shfl_up(acc, off);
            if (tid >= off) acc += t;
        }
        sexcl[tid] = acc - v;
        int node = b * 64 + tid;
        if (node < n) {
            startp[node] = s + (acc - v);
            dinv[node] = rsqrtf((float)v + 1.0f);   // +1 self-loop
        }
    }
    if (b == 0 && tid == 0) startp[n] = e;
    __syncthreads();
    if (tid < 64) scnt[tid] = sexcl[tid];   // reuse as cursor
    __syncthreads();
    for (int i = s + tid; i < s1; i += 256) {
        int2 r = eb[i];
        int cl = (r.y >> 26) & 63;
        int p = atomicAdd(&scnt[cl], 1);
        srow[s + p] = r.x;
        seid[s + p] = r.y & 0x03FFFFFF;
    }
}

// ==================== degree / dinv (fallback path only) ====================
__global__ void k_deg_count(const int* __restrict__ col, int* __restrict__ cnt, int e) {
    int i = blockIdx.x * blockDim.x + threadIdx.x;
    if (i < e) atomicAdd(&cnt[col[i]], 1);
}
__global__ void k_dinv(const int* __restrict__ cnt, float* __restrict__ dinv, int n) {
    int i = blockIdx.x * blockDim.x + threadIdx.x;
    if (i < n) dinv[i] = rsqrtf((float)cnt[i] + 1.0f);
}

// ==================== small GEMM: out[n][OUT] = in[n][K] @ W[K][OUT] ====================
template<int K, int OUT, bool BIAS, bool RELU, bool SCALE>
__launch_bounds__(256)
__global__ void k_gemm(const float* __restrict__ in, const float* __restrict__ W,
                       const float* __restrict__ b, const float* __restrict__ scale,
                       float* __restrict__ out, int n) {
    constexpr int NPB = 1024 / OUT;
    constexpr int GS  = 256 / OUT;
    __shared__ float sW[K * OUT];
    __shared__ float sX[NPB][K + 1];

    const int tid  = threadIdx.x;
    const int base = blockIdx.x * NPB;

    for (int i = tid; i < K * OUT; i += 256) sW[i] = W[i];
    for (int i = tid; i < NPB * K; i += 256) {
        int m = i / K, k = i - m * K;
        int node = base + m;
        sX[m][k] = (node < n) ? in[(long)node * K + k] : 0.0f;
    }
    __syncthreads();

    const int ch = tid % OUT;
    const int g  = tid / OUT;

    float acc[4] = {0.f, 0.f, 0.f, 0.f};
    #pragma unroll 4
    for (int k = 0; k < K; ++k) {
        float w = sW[k * OUT + ch];
        #pragma unroll
        for (int j = 0; j < 4; ++j)
            acc[j] += sX[g + j * GS][k] * w;
    }

    #pragma unroll
    for (int j = 0; j < 4; ++j) {
        int node = base + g + j * GS;
        if (node < n) {
            float v = acc[j];
            if (BIAS) v += b[ch];
            if (RELU) v = fmaxf(v, 0.0f);
            if (SCALE) v *= scale[node];
            out[(long)node * OUT + ch] = v;
        }
    }
}

// ==================== gather-reduce conv (no atomics) ====================
// out[c] = relu(dinv[c] * (sum_{r in N(c)} hs[r] + hs[c]) + b)   where hs = h*dinv
__global__ void k_gather_conv(const int* __restrict__ start, const int* __restrict__ srow,
                              const float* __restrict__ hs, const float* __restrict__ dinv,
                              const float* __restrict__ b, float* __restrict__ out, int n) {
    int node = blockIdx.x * 4 + (threadIdx.x >> 6);
    if (node >= n) return;
    int lane = threadIdx.x & 63;
    int s = start[node], e2 = start[node + 1];
    float acc = hs[(long)node * 64 + lane];   // self-loop
    for (int base = s; base < e2; base += 64) {
        int rem = e2 - base;
        int m = rem < 64 ? rem : 64;
        int rj = (lane < m) ? srow[base + lane] : 0;
        int j = 0;
        for (; j + 8 <= m; j += 8) {
            int r0 = __shfl(rj, j);
            int r1 = __shfl(rj, j + 1);
            int r2 = __shfl(rj, j + 2);
            int r3 = __shfl(rj, j + 3);
            int r4 = __shfl(rj, j + 4);
            int r5 = __shfl(rj, j + 5);
            int r6 = __shfl(rj, j + 6);
            int r7 = __shfl(rj, j + 7);
            float a0 = hs[(long)r0 * 64 + lane];
            float a1 = hs[(long)r1 * 64 + lane];
            float a2 = hs[(long)r2 * 64 + lane];
            float a3 = hs[(long)r3 * 64 + lane];
            float a4 = hs[(long)r4 * 64 + lane];
            float a5 = hs[(long)r5 * 64 + lane];
            float a6 = hs[(long)r6 * 64 + lane];
            float a7 = hs[(long)r7 * 64 + lane];
            acc += a0; acc += a1; acc += a2; acc += a3;
            acc += a4; acc += a5; acc += a6; acc += a7;
        }
        for (; j < m; ++j) {
            int r = __shfl(rj, j);
            acc += hs[(long)r * 64 + lane];
        }
    }
    out[(long)node * 64 + lane] = fmaxf(acc * dinv[node] + b[lane], 0.0f);
}

// ==================== edge scores via CSR ====================
__global__ void k_edge_scores_csr(const int* __restrict__ start, const int* __restrict__ srow,
                                  const int* __restrict__ eid, const float* __restrict__ nr,
                                  float* __restrict__ out, int n) {
    int node = blockIdx.x * 4 + (threadIdx.x >> 6);
    if (node >= n) return;
    int lane = threadIdx.x & 63;
    int sub = lane & 15;
    int eg  = lane >> 4;
    float4 c4 = *reinterpret_cast<const float4*>(&nr[(long)node * 64 + sub * 4]);
    int s = start[node], e2 = start[node + 1];
    for (int j = s + eg; j < e2; j += 4) {
        int r = srow[j];
        float4 a = *reinterpret_cast<const float4*>(&nr[(long)r * 64 + sub * 4]);
        float v = a.x * c4.x + a.y * c4.y + a.z * c4.z + a.w * c4.w;
        v += __shfl_xor(v, 1);
        v += __shfl_xor(v, 2);
        v += __shfl_xor(v, 4);
        v += __shfl_xor(v, 8);
        if (sub == 0) out[eid[j]] = v;
    }
}

// ==================== fallback path (small ws): atomic scatter ====================
__global__ void k_scatter_simple(const int* __restrict__ row, const int* __restrict__ col,
                                 const float* __restrict__ hs, float* __restrict__ acc, int e) {
    int t = blockIdx.x * blockDim.x + threadIdx.x;
    int lane = t & 63;
    int eidx = t >> 6;
    if (eidx >= e) return;
    int r = row[eidx], c = col[eidx];
    atomicAdd(&acc[(long)c * 64 + lane], hs[(long)r * 64 + lane]);
}
__global__ void k_epilogue2(float* __restrict__ acc, const float* __restrict__ hs,
                            const float* __restrict__ dinv, const float* __restrict__ b, int n) {
    int i = blockIdx.x * blockDim.x + threadIdx.x;
    if (i >= n * 64) return;
    int node = i >> 6, ch = i & 63;
    acc[i] = fmaxf(dinv[node] * (acc[i] + hs[i]) + b[ch], 0.0f);
}
__global__ void k_edge_scores_orig(const int* __restrict__ row, const int* __restrict__ col,
                                   const float* __restrict__ nr, float* __restrict__ out, int e) {
    int t = blockIdx.x * blockDim.x + threadIdx.x;
    int sub = t & 15;
    int eidx = t >> 4;
    if (eidx >= e) return;
    int r = row[eidx], c = col[eidx];
    float4 a  = *reinterpret_cast<const float4*>(&nr[(long)r * 64 + sub * 4]);
    float4 bb = *reinterpret_cast<const float4*>(&nr[(long)c * 64 + sub * 4]);
    float s = a.x * bb.x + a.y * bb.y + a.z * bb.z + a.w * bb.w;
    s += __shfl_xor(s, 1);
    s += __shfl_xor(s, 2);
    s += __shfl_xor(s, 4);
    s += __shfl_xor(s, 8);
    if (sub == 0) out[eidx] = s;
}

extern "C" void kernel_launch(void* const* d_in, const int* in_sizes, int n_in,
                              void* d_out, int out_size, void* d_ws, size_t ws_size,
                              hipStream_t stream) {
    const float* x   = (const float*)d_in[0];
    const int*   ei  = (const int*)d_in[1];
    const float* W1  = (const float*)d_in[2];
    const float* b1  = (const float*)d_in[3];
    const float* W2  = (const float*)d_in[4];
    const float* b2  = (const float*)d_in[5];
    const float* Wd1 = (const float*)d_in[6];
    const float* bd1 = (const float*)d_in[7];
    const float* Wd2 = (const float*)d_in[8];
    const float* bd2 = (const float*)d_in[9];

    const int N = in_sizes[0] / 128;
    const int E = in_sizes[1] / 2;
    const int* row = ei;
    const int* col = ei + E;
    const int n64 = N * 64;
    const int B = (N + 63) >> 6;          // buckets of 64 nodes

    // d_out layout: recon_x [N*128] | edge_scores [E] | node_repr [N*64]
    float* recon_out  = (float*)d_out;
    float* escore_out = recon_out + (long)N * 128;
    float* nr_out     = escore_out + E;

    // workspace layout
    float* dinv = (float*)d_ws;                 // N
    float* buf1 = dinv + N;                     // N*64 floats (aliased: int2 ebuck[E])
    float* buf2 = buf1 + (long)N * 64;          // N*64
    int* startp = (int*)(buf2 + (long)N * 64);  // N+1
    int* srow   = startp + N + 1;               // E
    int* seid   = srow + E;                     // E
    int* bcnt   = seid + E;                     // B
    int* bstart = bcnt + B;                     // B+1
    int* bcur   = bstart + B + 1;               // B
    int2* ebuck = (int2*)buf1;                  // E int2 (25.6MB == N*64 floats)

    size_t need_full = sizeof(float) * ((size_t)N + 2uL * n64)
                     + sizeof(int) * ((size_t)N + 1 + 2uL * E + 3uL * B + 1);
    bool csr_ok = (ws_size >= need_full) && (E < (1 << 26)) && ((long)E * 2 <= (long)n64)
                  && (B <= 4096);

    if (csr_ok) {
        // ---------- bucketed CSR build (write-local, no fp atomics anywhere) ----------
        k_zero_i<<<(B + 255) / 256, 256, 0, stream>>>(bcnt, B);
        k_bcount<<<(E + 255) / 256, 256, 0, stream>>>(col, bcnt, E);
        k_bscan<<<1, 1024, 0, stream>>>(bcnt, bstart, bcur, B);
        k_partition<<<(E + 255) / 256, 256, 0, stream>>>(row, col, bcur, ebuck, E);
        k_bucket_csr<<<B, 256, 0, stream>>>(ebuck, bstart, srow, seid, startp, dinv, N, E);

        // layer 1: hs1 = (x@W1)*dinv  (overwrites ebuck region - build is done)
        k_gemm<128, 64, false, false, true><<<(N + 15) / 16, 256, 0, stream>>>(x, W1, nullptr, dinv, buf1, N);
        k_gather_conv<<<(N + 3) / 4, 256, 0, stream>>>(startp, srow, buf1, dinv, b1, buf2, N);
        // layer 2
        k_gemm<64, 64, false, false, true><<<(N + 15) / 16, 256, 0, stream>>>(buf2, W2, nullptr, dinv, buf1, N);
        k_gather_conv<<<(N + 3) / 4, 256, 0, stream>>>(startp, srow, buf1, dinv, b2, nr_out, N);
        // decoder
        k_gemm<64, 64, true, true, false><<<(N + 15) / 16, 256, 0, stream>>>(nr_out, Wd1, bd1, nullptr, buf2, N);
        k_gemm<64, 128, true, false, false><<<(N + 7) / 8, 256, 0, stream>>>(buf2, Wd2, bd2, nullptr, recon_out, N);
        // edge scores
        k_edge_scores_csr<<<(N + 3) / 4, 256, 0, stream>>>(startp, srow, seid, nr_out, escore_out, N);
    } else {
        // ---------- fallback: atomic scatter ----------
        int* cnt = startp;
        k_zero_i<<<(N + 255) / 256, 256, 0, stream>>>(cnt, N);
        k_deg_count<<<(E + 255) / 256, 256, 0, stream>>>(col, cnt, E);
        k_dinv<<<(N + 255) / 256, 256, 0, stream>>>(cnt, dinv, N);
        k_zero_f<<<(n64 + 255) / 256, 256, 0, stream>>>(buf2, n64);
        k_zero_f<<<(n64 + 255) / 256, 256, 0, stream>>>(nr_out, n64);

        k_gemm<128, 64, false, false, true><<<(N + 15) / 16, 256, 0, stream>>>(x, W1, nullptr, dinv, buf1, N);
        k_scatter_simple<<<((long)E * 64 + 255) / 256, 256, 0, stream>>>(row, col, buf1, buf2, E);
        k_epilogue2<<<(n64 + 255) / 256, 256, 0, stream>>>(buf2, buf1, dinv, b1, N);
        k_gemm<64, 64, false, false, true><<<(N + 15) / 16, 256, 0, stream>>>(buf2, W2, nullptr, dinv, buf1, N);
        k_scatter_simple<<<((long)E * 64 + 255) / 256, 256, 0, stream>>>(row, col, buf1, nr_out, E);
        k_epilogue2<<<(n64 + 255) / 256, 256, 0, stream>>>(nr_out, buf1, dinv, b2, N);
        k_gemm<64, 64, true, true, false><<<(N + 15) / 16, 256, 0, stream>>>(nr_out, Wd1, bd1, nullptr, buf2, N);
        k_gemm<64, 128, true, false, false><<<(N + 7) / 8, 256, 0, stream>>>(buf2, Wd2, bd2, nullptr, recon_out, N);
        k_edge_scores_orig<<<((long)E * 16 + 255) / 256, 256, 0, stream>>>(row, col, nr_out, escore_out, E);
    }
}

// Round 9
// 955.272 us; speedup vs baseline: 1.8060x; 1.8060x over previous
//
#include <hip/hip_runtime.h>

// ==================== utility ====================
__global__ void k_zero_i(int* __restrict__ p, int n) {
    int i = blockIdx.x * blockDim.x + threadIdx.x;
    if (i < n) p[i] = 0;
}
__global__ void k_zero_f(float* __restrict__ p, long n) {
    long i = blockIdx.x * (long)blockDim.x + threadIdx.x;
    if (i < n) p[i] = 0.0f;
}

// ==================== atomic-free CSR build ====================
// buckets of 512 nodes: bucket = col >> 9. chunks of 16384 edges.
// hist[bucket * nchunks + chunk] -> exclusive scan -> disjoint write windows.

#define CH 16384

// pass 1: per-chunk LDS histogram (no global atomics)
__global__ void k_hist(const int* __restrict__ col, int* __restrict__ hist,
                       int e, int B, int nchunks) {
    extern __shared__ int lh[];
    for (int i = threadIdx.x; i < B; i += 256) lh[i] = 0;
    __syncthreads();
    const int base = blockIdx.x * CH;
    const int end = min(e, base + CH);
    for (int i = base + threadIdx.x; i < end; i += 256)
        atomicAdd(&lh[col[i] >> 9], 1);
    __syncthreads();
    for (int b = threadIdx.x; b < B; b += 256)
        hist[(long)b * nchunks + blockIdx.x] = lh[b];
}

// pass 2: single-block exclusive scan of the whole (bucket-major) table, in place
__global__ void k_scan_tbl(int* __restrict__ hist, long T) {
    __shared__ int ws[1024];
    const int tid = threadIdx.x;
    const long per = (T + 1023) >> 10;
    const long s = tid * per;
    const long e2 = min(T, s + per);
    int sum = 0;
    for (long i = s; i < e2; ++i) sum += hist[i];
    ws[tid] = sum;
    __syncthreads();
    for (int off = 1; off < 1024; off <<= 1) {
        int add = (tid >= off) ? ws[tid - off] : 0;
        __syncthreads();
        ws[tid] += add;
        __syncthreads();
    }
    int run = ws[tid] - sum;   // exclusive prefix of this thread's range
    for (long i = s; i < e2; ++i) { int t = hist[i]; hist[i] = run; run += t; }
}

// pass 3: re-read chunk, rank via LDS cursors, ONE write per edge into a
// private (bucket,chunk) window. No global atomics, no cross-block contention.
__global__ void k_part2(const int* __restrict__ row, const int* __restrict__ col,
                        const int* __restrict__ hist, int2* __restrict__ eb,
                        int e, int B, int nchunks) {
    extern __shared__ int cur[];
    const int bId = blockIdx.x;
    for (int b = threadIdx.x; b < B; b += 256)
        cur[b] = hist[(long)b * nchunks + bId];
    __syncthreads();
    const int base = bId * CH;
    const int end = min(e, base + CH);
    for (int i = base + threadIdx.x; i < end; i += 256) {
        int c = col[i];
        int p = atomicAdd(&cur[c >> 9], 1);
        eb[p] = make_int2(row[i], ((c & 511) << 22) | i);   // eid < 2^22 (guarded)
    }
}

// pass 4: one block per bucket (512 nodes, edges L2-resident):
// LDS count -> scan -> emit startp/dinv -> scatter srow/seid within window.
__global__ void k_bucket_csr(const int2* __restrict__ eb, const int* __restrict__ hist,
                             int nchunks, int* __restrict__ srow, int* __restrict__ seid,
                             int* __restrict__ startp, float* __restrict__ dinv,
                             int n, int e, int B) {
    __shared__ int scnt[512];
    __shared__ int sex[512];
    const int b = blockIdx.x;
    const int tid = threadIdx.x;
    for (int i = tid; i < 512; i += 256) scnt[i] = 0;
    __syncthreads();
    const int s = hist[(long)b * nchunks];
    const int s1 = (b + 1 < B) ? hist[(long)(b + 1) * nchunks] : e;
    for (int i = s + tid; i < s1; i += 256)
        atomicAdd(&scnt[(eb[i].y >> 22) & 511], 1);
    __syncthreads();
    if (tid < 64) {   // wave 0: scan 512 counts (8 per lane, serial + shuffle)
        int vals[8];
        int tot = 0;
        #pragma unroll
        for (int k = 0; k < 8; ++k) { vals[k] = scnt[tid * 8 + k]; tot += vals[k]; }
        int acc = tot;
        #pragma unroll
        for (int off = 1; off < 64; off <<= 1) {
            int t = __shfl_up(acc, off);
            if (tid >= off) acc += t;
        }
        int excl = acc - tot;
        #pragma unroll
        for (int k = 0; k < 8; ++k) {
            sex[tid * 8 + k] = excl;
            int node = b * 512 + tid * 8 + k;
            if (node < n) {
                startp[node] = s + excl;
                dinv[node] = rsqrtf((float)vals[k] + 1.0f);   // +1 self-loop
            }
            excl += vals[k];
        }
    }
    if (b == 0 && tid == 0) startp[n] = e;
    __syncthreads();
    for (int i = tid; i < 512; i += 256) scnt[i] = sex[i];   // cursors
    __syncthreads();
    for (int i = s + tid; i < s1; i += 256) {
        int2 r = eb[i];
        int cl = (r.y >> 22) & 511;
        int p = atomicAdd(&scnt[cl], 1);
        srow[s + p] = r.x;
        seid[s + p] = r.y & 0x3FFFFF;
    }
}

// ==================== degree / dinv (fallback path only) ====================
__global__ void k_deg_count(const int* __restrict__ col, int* __restrict__ cnt, int e) {
    int i = blockIdx.x * blockDim.x + threadIdx.x;
    if (i < e) atomicAdd(&cnt[col[i]], 1);
}
__global__ void k_dinv(const int* __restrict__ cnt, float* __restrict__ dinv, int n) {
    int i = blockIdx.x * blockDim.x + threadIdx.x;
    if (i < n) dinv[i] = rsqrtf((float)cnt[i] + 1.0f);
}

// ==================== small GEMM: out[n][OUT] = in[n][K] @ W[K][OUT] ====================
template<int K, int OUT, bool BIAS, bool RELU, bool SCALE>
__launch_bounds__(256)
__global__ void k_gemm(const float* __restrict__ in, const float* __restrict__ W,
                       const float* __restrict__ b, const float* __restrict__ scale,
                       float* __restrict__ out, int n) {
    constexpr int NPB = 1024 / OUT;
    constexpr int GS  = 256 / OUT;
    __shared__ float sW[K * OUT];
    __shared__ float sX[NPB][K + 1];

    const int tid  = threadIdx.x;
    const int base = blockIdx.x * NPB;

    for (int i = tid; i < K * OUT; i += 256) sW[i] = W[i];
    for (int i = tid; i < NPB * K; i += 256) {
        int m = i / K, k = i - m * K;
        int node = base + m;
        sX[m][k] = (node < n) ? in[(long)node * K + k] : 0.0f;
    }
    __syncthreads();

    const int ch = tid % OUT;
    const int g  = tid / OUT;

    float acc[4] = {0.f, 0.f, 0.f, 0.f};
    #pragma unroll 4
    for (int k = 0; k < K; ++k) {
        float w = sW[k * OUT + ch];
        #pragma unroll
        for (int j = 0; j < 4; ++j)
            acc[j] += sX[g + j * GS][k] * w;
    }

    #pragma unroll
    for (int j = 0; j < 4; ++j) {
        int node = base + g + j * GS;
        if (node < n) {
            float v = acc[j];
            if (BIAS) v += b[ch];
            if (RELU) v = fmaxf(v, 0.0f);
            if (SCALE) v *= scale[node];
            out[(long)node * OUT + ch] = v;
        }
    }
}

// ==================== gather-reduce conv (no atomics) ====================
__global__ void k_gather_conv(const int* __restrict__ start, const int* __restrict__ srow,
                              const float* __restrict__ hs, const float* __restrict__ dinv,
                              const float* __restrict__ b, float* __restrict__ out, int n) {
    int node = blockIdx.x * 4 + (threadIdx.x >> 6);
    if (node >= n) return;
    int lane = threadIdx.x & 63;
    int s = start[node], e2 = start[node + 1];
    float acc = hs[(long)node * 64 + lane];   // self-loop
    for (int base = s; base < e2; base += 64) {
        int rem = e2 - base;
        int m = rem < 64 ? rem : 64;
        int rj = (lane < m) ? srow[base + lane] : 0;
        int j = 0;
        for (; j + 8 <= m; j += 8) {
            int r0 = __shfl(rj, j);
            int r1 = __shfl(rj, j + 1);
            int r2 = __shfl(rj, j + 2);
            int r3 = __shfl(rj, j + 3);
            int r4 = __shfl(rj, j + 4);
            int r5 = __shfl(rj, j + 5);
            int r6 = __shfl(rj, j + 6);
            int r7 = __shfl(rj, j + 7);
            float a0 = hs[(long)r0 * 64 + lane];
            float a1 = hs[(long)r1 * 64 + lane];
            float a2 = hs[(long)r2 * 64 + lane];
            float a3 = hs[(long)r3 * 64 + lane];
            float a4 = hs[(long)r4 * 64 + lane];
            float a5 = hs[(long)r5 * 64 + lane];
            float a6 = hs[(long)r6 * 64 + lane];
            float a7 = hs[(long)r7 * 64 + lane];
            acc += a0; acc += a1; acc += a2; acc += a3;
            acc += a4; acc += a5; acc += a6; acc += a7;
        }
        for (; j < m; ++j) {
            int r = __shfl(rj, j);
            acc += hs[(long)r * 64 + lane];
        }
    }
    out[(long)node * 64 + lane] = fmaxf(acc * dinv[node] + b[lane], 0.0f);
}

// ==================== edge scores via CSR ====================
__global__ void k_edge_scores_csr(const int* __restrict__ start, const int* __restrict__ srow,
                                  const int* __restrict__ eid, const float* __restrict__ nr,
                                  float* __restrict__ out, int n) {
    int node = blockIdx.x * 4 + (threadIdx.x >> 6);
    if (node >= n) return;
    int lane = threadIdx.x & 63;
    int sub = lane & 15;
    int eg  = lane >> 4;
    float4 c4 = *reinterpret_cast<const float4*>(&nr[(long)node * 64 + sub * 4]);
    int s = start[node], e2 = start[node + 1];
    for (int j = s + eg; j < e2; j += 4) {
        int r = srow[j];
        float4 a = *reinterpret_cast<const float4*>(&nr[(long)r * 64 + sub * 4]);
        float v = a.x * c4.x + a.y * c4.y + a.z * c4.z + a.w * c4.w;
        v += __shfl_xor(v, 1);
        v += __shfl_xor(v, 2);
        v += __shfl_xor(v, 4);
        v += __shfl_xor(v, 8);
        if (sub == 0) out[eid[j]] = v;
    }
}

// ==================== fallback path (small ws): atomic scatter ====================
__global__ void k_scatter_simple(const int* __restrict__ row, const int* __restrict__ col,
                                 const float* __restrict__ hs, float* __restrict__ acc, int e) {
    int t = blockIdx.x * blockDim.x + threadIdx.x;
    int lane = t & 63;
    int eidx = t >> 6;
    if (eidx >= e) return;
    int r = row[eidx], c = col[eidx];
    atomicAdd(&acc[(long)c * 64 + lane], hs[(long)r * 64 + lane]);
}
__global__ void k_epilogue2(float* __restrict__ acc, const float* __restrict__ hs,
                            const float* __restrict__ dinv, const float* __restrict__ b, int n) {
    int i = blockIdx.x * blockDim.x + threadIdx.x;
    if (i >= n * 64) return;
    int node = i >> 6, ch = i & 63;
    acc[i] = fmaxf(dinv[node] * (acc[i] + hs[i]) + b[ch], 0.0f);
}
__global__ void k_edge_scores_orig(const int* __restrict__ row, const int* __restrict__ col,
                                   const float* __restrict__ nr, float* __restrict__ out, int e) {
    int t = blockIdx.x * blockDim.x + threadIdx.x;
    int sub = t & 15;
    int eidx = t >> 4;
    if (eidx >= e) return;
    int r = row[eidx], c = col[eidx];
    float4 a  = *reinterpret_cast<const float4*>(&nr[(long)r * 64 + sub * 4]);
    float4 bb = *reinterpret_cast<const float4*>(&nr[(long)c * 64 + sub * 4]);
    float s = a.x * bb.x + a.y * bb.y + a.z * bb.z + a.w * bb.w;
    s += __shfl_xor(s, 1);
    s += __shfl_xor(s, 2);
    s += __shfl_xor(s, 4);
    s += __shfl_xor(s, 8);
    if (sub == 0) out[eidx] = s;
}

extern "C" void kernel_launch(void* const* d_in, const int* in_sizes, int n_in,
                              void* d_out, int out_size, void* d_ws, size_t ws_size,
                              hipStream_t stream) {
    const float* x   = (const float*)d_in[0];
    const int*   ei  = (const int*)d_in[1];
    const float* W1  = (const float*)d_in[2];
    const float* b1  = (const float*)d_in[3];
    const float* W2  = (const float*)d_in[4];
    const float* b2  = (const float*)d_in[5];
    const float* Wd1 = (const float*)d_in[6];
    const float* bd1 = (const float*)d_in[7];
    const float* Wd2 = (const float*)d_in[8];
    const float* bd2 = (const float*)d_in[9];

    const int N = in_sizes[0] / 128;
    const int E = in_sizes[1] / 2;
    const int* row = ei;
    const int* col = ei + E;
    const int n64 = N * 64;
    const int B = (N + 511) >> 9;              // buckets of 512 nodes
    const int nchunks = (E + CH - 1) / CH;     // chunks of 16384 edges

    // d_out layout: recon_x [N*128] | edge_scores [E] | node_repr [N*64]
    float* recon_out  = (float*)d_out;
    float* escore_out = recon_out + (long)N * 128;
    float* nr_out     = escore_out + E;

    // workspace layout
    float* dinv = (float*)d_ws;                 // N
    float* buf1 = dinv + N;                     // N*64 floats (aliased: int2 ebuck[E])
    float* buf2 = buf1 + (long)N * 64;          // N*64
    int* startp = (int*)(buf2 + (long)N * 64);  // N+1
    int* srow   = startp + N + 1;               // E
    int* seid   = srow + E;                     // E
    int* hist   = seid + E;                     // B*nchunks
    int2* ebuck = (int2*)buf1;                  // E int2 (fits: E*2 <= N*64, guarded)

    size_t need_full = sizeof(float) * ((size_t)N + 2uL * n64)
                     + sizeof(int) * ((size_t)N + 1 + 2uL * E + (size_t)B * nchunks);
    bool csr_ok = (ws_size >= need_full) && (E < (1 << 22)) && ((long)E * 2 <= (long)n64)
                  && (B <= 2048);

    if (csr_ok) {
        // ---------- atomic-free CSR build ----------
        k_hist<<<nchunks, 256, B * sizeof(int), stream>>>(col, hist, E, B, nchunks);
        k_scan_tbl<<<1, 1024, 0, stream>>>(hist, (long)B * nchunks);
        k_part2<<<nchunks, 256, B * sizeof(int), stream>>>(row, col, hist, ebuck, E, B, nchunks);
        k_bucket_csr<<<B, 256, 0, stream>>>(ebuck, hist, nchunks, srow, seid, startp, dinv, N, E, B);

        // layer 1: hs1 = (x@W1)*dinv  (overwrites ebuck region - build is done)
        k_gemm<128, 64, false, false, true><<<(N + 15) / 16, 256, 0, stream>>>(x, W1, nullptr, dinv, buf1, N);
        k_gather_conv<<<(N + 3) / 4, 256, 0, stream>>>(startp, srow, buf1, dinv, b1, buf2, N);
        // layer 2
        k_gemm<64, 64, false, false, true><<<(N + 15) / 16, 256, 0, stream>>>(buf2, W2, nullptr, dinv, buf1, N);
        k_gather_conv<<<(N + 3) / 4, 256, 0, stream>>>(startp, srow, buf1, dinv, b2, nr_out, N);
        // decoder
        k_gemm<64, 64, true, true, false><<<(N + 15) / 16, 256, 0, stream>>>(nr_out, Wd1, bd1, nullptr, buf2, N);
        k_gemm<64, 128, true, false, false><<<(N + 7) / 8, 256, 0, stream>>>(buf2, Wd2, bd2, nullptr, recon_out, N);
        // edge scores
        k_edge_scores_csr<<<(N + 3) / 4, 256, 0, stream>>>(startp, srow, seid, nr_out, escore_out, N);
    } else {
        // ---------- fallback: atomic scatter ----------
        int* cnt = startp;
        k_zero_i<<<(N + 255) / 256, 256, 0, stream>>>(cnt, N);
        k_deg_count<<<(E + 255) / 256, 256, 0, stream>>>(col, cnt, E);
        k_dinv<<<(N + 255) / 256, 256, 0, stream>>>(cnt, dinv, N);
        k_zero_f<<<(n64 + 255) / 256, 256, 0, stream>>>(buf2, n64);
        k_zero_f<<<(n64 + 255) / 256, 256, 0, stream>>>(nr_out, n64);

        k_gemm<128, 64, false, false, true><<<(N + 15) / 16, 256, 0, stream>>>(x, W1, nullptr, dinv, buf1, N);
        k_scatter_simple<<<((long)E * 64 + 255) / 256, 256, 0, stream>>>(row, col, buf1, buf2, E);
        k_epilogue2<<<(n64 + 255) / 256, 256, 0, stream>>>(buf2, buf1, dinv, b1, N);
        k_gemm<64, 64, false, false, true><<<(N + 15) / 16, 256, 0, stream>>>(buf2, W2, nullptr, dinv, buf1, N);
        k_scatter_simple<<<((long)E * 64 + 255) / 256, 256, 0, stream>>>(row, col, buf1, nr_out, E);
        k_epilogue2<<<(n64 + 255) / 256, 256, 0, stream>>>(nr_out, buf1, dinv, b2, N);
        k_gemm<64, 64, true, true, false><<<(N + 15) / 16, 256, 0, stream>>>(nr_out, Wd1, bd1, nullptr, buf2, N);
        k_gemm<64, 128, true, false, false><<<(N + 7) / 8, 256, 0, stream>>>(buf2, Wd2, bd2, nullptr, recon_out, N);
        k_edge_scores_orig<<<((long)E * 16 + 255) / 256, 256, 0, stream>>>(row, col, nr_out, escore_out, E);
    }
}

// Round 11
// 938.951 us; speedup vs baseline: 1.8373x; 1.0174x over previous
//
#include <hip/hip_runtime.h>

// ==================== utility ====================
__global__ void k_zero_i(int* __restrict__ p, int n) {
    int i = blockIdx.x * blockDim.x + threadIdx.x;
    if (i < n) p[i] = 0;
}
__global__ void k_zero_f(float* __restrict__ p, long n) {
    long i = blockIdx.x * (long)blockDim.x + threadIdx.x;
    if (i < n) p[i] = 0.0f;
}

// ==================== atomic-free CSR build ====================
// buckets of 512 nodes: bucket = col >> 9. chunks of 16384 edges.
// hist[bucket * nchunks + chunk] -> exclusive scan -> disjoint write windows.

#define CH 16384

// pass 1: per-chunk LDS histogram (no global atomics)
__global__ void k_hist(const int* __restrict__ col, int* __restrict__ hist,
                       int e, int B, int nchunks) {
    extern __shared__ int lh[];
    for (int i = threadIdx.x; i < B; i += 256) lh[i] = 0;
    __syncthreads();
    const int base = blockIdx.x * CH;
    const int end = min(e, base + CH);
    for (int i = base + threadIdx.x; i < end; i += 256)
        atomicAdd(&lh[col[i] >> 9], 1);
    __syncthreads();
    for (int b = threadIdx.x; b < B; b += 256)
        hist[(long)b * nchunks + blockIdx.x] = lh[b];
}

// pass 2: single-block exclusive scan of the whole (bucket-major) table, in place
__global__ void k_scan_tbl(int* __restrict__ hist, long T) {
    __shared__ int ws[1024];
    const int tid = threadIdx.x;
    const long per = (T + 1023) >> 10;
    const long s = tid * per;
    const long e2 = min(T, s + per);
    int sum = 0;
    for (long i = s; i < e2; ++i) sum += hist[i];
    ws[tid] = sum;
    __syncthreads();
    for (int off = 1; off < 1024; off <<= 1) {
        int add = (tid >= off) ? ws[tid - off] : 0;
        __syncthreads();
        ws[tid] += add;
        __syncthreads();
    }
    int run = ws[tid] - sum;   // exclusive prefix of this thread's range
    for (long i = s; i < e2; ++i) { int t = hist[i]; hist[i] = run; run += t; }
}

// pass 3: re-read chunk, rank via LDS cursors, ONE write per edge into a
// private (bucket,chunk) window. No global atomics, no cross-block contention.
__global__ void k_part2(const int* __restrict__ row, const int* __restrict__ col,
                        const int* __restrict__ hist, int2* __restrict__ eb,
                        int e, int B, int nchunks) {
    extern __shared__ int cur[];
    const int bId = blockIdx.x;
    for (int b = threadIdx.x; b < B; b += 256)
        cur[b] = hist[(long)b * nchunks + bId];
    __syncthreads();
    const int base = bId * CH;
    const int end = min(e, base + CH);
    for (int i = base + threadIdx.x; i < end; i += 256) {
        int c = col[i];
        int p = atomicAdd(&cur[c >> 9], 1);
        eb[p] = make_int2(row[i], ((c & 511) << 22) | i);   // eid < 2^22 (guarded)
    }
}

// pass 4: one block per bucket (512 nodes, edges L2-resident):
// LDS count -> scan -> emit startp/dinv -> scatter srow/seid within window.
__global__ void k_bucket_csr(const int2* __restrict__ eb, const int* __restrict__ hist,
                             int nchunks, int* __restrict__ srow, int* __restrict__ seid,
                             int* __restrict__ startp, float* __restrict__ dinv,
                             int n, int e, int B) {
    __shared__ int scnt[512];
    __shared__ int sex[512];
    const int b = blockIdx.x;
    const int tid = threadIdx.x;
    for (int i = tid; i < 512; i += 256) scnt[i] = 0;
    __syncthreads();
    const int s = hist[(long)b * nchunks];
    const int s1 = (b + 1 < B) ? hist[(long)(b + 1) * nchunks] : e;
    for (int i = s + tid; i < s1; i += 256)
        atomicAdd(&scnt[(eb[i].y >> 22) & 511], 1);
    __syncthreads();
    if (tid < 64) {   // wave 0: scan 512 counts (8 per lane, serial + shuffle)
        int vals[8];
        int tot = 0;
        #pragma unroll
        for (int k = 0; k < 8; ++k) { vals[k] = scnt[tid * 8 + k]; tot += vals[k]; }
        int acc = tot;
        #pragma unroll
        for (int off = 1; off < 64; off <<= 1) {
            int t = __shfl_up(acc, off);
            if (tid >= off) acc += t;
        }
        int excl = acc - tot;
        #pragma unroll
        for (int k = 0; k < 8; ++k) {
            sex[tid * 8 + k] = excl;
            int node = b * 512 + tid * 8 + k;
            if (node < n) {
                startp[node] = s + excl;
                dinv[node] = rsqrtf((float)vals[k] + 1.0f);   // +1 self-loop
            }
            excl += vals[k];
        }
    }
    if (b == 0 && tid == 0) startp[n] = e;
    __syncthreads();
    for (int i = tid; i < 512; i += 256) scnt[i] = sex[i];   // cursors
    __syncthreads();
    for (int i = s + tid; i < s1; i += 256) {
        int2 r = eb[i];
        int cl = (r.y >> 22) & 511;
        int p = atomicAdd(&scnt[cl], 1);
        srow[s + p] = r.x;
        seid[s + p] = r.y & 0x3FFFFF;
    }
}

// ==================== degree / dinv (fallback path only) ====================
__global__ void k_deg_count(const int* __restrict__ col, int* __restrict__ cnt, int e) {
    int i = blockIdx.x * blockDim.x + threadIdx.x;
    if (i < e) atomicAdd(&cnt[col[i]], 1);
}
__global__ void k_dinv(const int* __restrict__ cnt, float* __restrict__ dinv, int n) {
    int i = blockIdx.x * blockDim.x + threadIdx.x;
    if (i < n) dinv[i] = rsqrtf((float)cnt[i] + 1.0f);
}

// ==================== small GEMM: out[n][OUT] = in[n][K] @ W[K][OUT] ====================
template<int K, int OUT, bool BIAS, bool RELU, bool SCALE>
__launch_bounds__(256)
__global__ void k_gemm(const float* __restrict__ in, const float* __restrict__ W,
                       const float* __restrict__ b, const float* __restrict__ scale,
                       float* __restrict__ out, int n) {
    constexpr int NPB = 1024 / OUT;
    constexpr int GS  = 256 / OUT;
    __shared__ float sW[K * OUT];
    __shared__ float sX[NPB][K + 1];

    const int tid  = threadIdx.x;
    const int base = blockIdx.x * NPB;

    for (int i = tid; i < K * OUT; i += 256) sW[i] = W[i];
    for (int i = tid; i < NPB * K; i += 256) {
        int m = i / K, k = i - m * K;
        int node = base + m;
        sX[m][k] = (node < n) ? in[(long)node * K + k] : 0.0f;
    }
    __syncthreads();

    const int ch = tid % OUT;
    const int g  = tid / OUT;

    float acc[4] = {0.f, 0.f, 0.f, 0.f};
    #pragma unroll 4
    for (int k = 0; k < K; ++k) {
        float w = sW[k * OUT + ch];
        #pragma unroll
        for (int j = 0; j < 4; ++j)
            acc[j] += sX[g + j * GS][k] * w;
    }

    #pragma unroll
    for (int j = 0; j < 4; ++j) {
        int node = base + g + j * GS;
        if (node < n) {
            float v = acc[j];
            if (BIAS) v += b[ch];
            if (RELU) v = fmaxf(v, 0.0f);
            if (SCALE) v *= scale[node];
            out[(long)node * OUT + ch] = v;
        }
    }
}

// ==================== gather-reduce conv (no atomics) ====================
__global__ void k_gather_conv(const int* __restrict__ start, const int* __restrict__ srow,
                              const float* __restrict__ hs, const float* __restrict__ dinv,
                              const float* __restrict__ b, float* __restrict__ out, int n) {
    int node = blockIdx.x * 4 + (threadIdx.x >> 6);
    if (node >= n) return;
    int lane = threadIdx.x & 63;
    int s = start[node], e2 = start[node + 1];
    float acc = hs[(long)node * 64 + lane];   // self-loop
    for (int base = s; base < e2; base += 64) {
        int rem = e2 - base;
        int m = rem < 64 ? rem : 64;
        int rj = (lane < m) ? srow[base + lane] : 0;
        int j = 0;
        for (; j + 8 <= m; j += 8) {
            int r0 = __shfl(rj, j);
            int r1 = __shfl(rj, j + 1);
            int r2 = __shfl(rj, j + 2);
            int r3 = __shfl(rj, j + 3);
            int r4 = __shfl(rj, j + 4);
            int r5 = __shfl(rj, j + 5);
            int r6 = __shfl(rj, j + 6);
            int r7 = __shfl(rj, j + 7);
            float a0 = hs[(long)r0 * 64 + lane];
            float a1 = hs[(long)r1 * 64 + lane];
            float a2 = hs[(long)r2 * 64 + lane];
            float a3 = hs[(long)r3 * 64 + lane];
            float a4 = hs[(long)r4 * 64 + lane];
            float a5 = hs[(long)r5 * 64 + lane];
            float a6 = hs[(long)r6 * 64 + lane];
            float a7 = hs[(long)r7 * 64 + lane];
            acc += a0; acc += a1; acc += a2; acc += a3;
            acc += a4; acc += a5; acc += a6; acc += a7;
        }
        for (; j < m; ++j) {
            int r = __shfl(rj, j);
            acc += hs[(long)r * 64 + lane];
        }
    }
    out[(long)node * 64 + lane] = fmaxf(acc * dinv[node] + b[lane], 0.0f);
}

// ==================== edge scores via CSR (4-way ILP unroll) ====================
// one node per 64-lane wave; 4 edge-groups x 16 lanes; each group keeps 4
// independent row-gathers in flight before reducing (latency hiding).
__launch_bounds__(256)
__global__ void k_edge_scores_csr(const int* __restrict__ start, const int* __restrict__ srow,
                                  const int* __restrict__ eid, const float* __restrict__ nr,
                                  float* __restrict__ out, int n) {
    int node = blockIdx.x * 4 + (threadIdx.x >> 6);
    if (node >= n) return;
    int lane = threadIdx.x & 63;
    int sub = lane & 15;
    int eg  = lane >> 4;
    float4 c4 = *reinterpret_cast<const float4*>(&nr[(long)node * 64 + sub * 4]);
    int s = start[node], e2 = start[node + 1];
    int j = s + eg;
    // main: 4 edges per group per iteration, loads batched before reduces
    for (; j + 12 < e2; j += 16) {
        int r0 = srow[j];
        int r1 = srow[j + 4];
        int r2 = srow[j + 8];
        int r3 = srow[j + 12];
        float4 a0 = *reinterpret_cast<const float4*>(&nr[(long)r0 * 64 + sub * 4]);
        float4 a1 = *reinterpret_cast<const float4*>(&nr[(long)r1 * 64 + sub * 4]);
        float4 a2 = *reinterpret_cast<const float4*>(&nr[(long)r2 * 64 + sub * 4]);
        float4 a3 = *reinterpret_cast<const float4*>(&nr[(long)r3 * 64 + sub * 4]);
        float v0 = a0.x * c4.x + a0.y * c4.y + a0.z * c4.z + a0.w * c4.w;
        float v1 = a1.x * c4.x + a1.y * c4.y + a1.z * c4.z + a1.w * c4.w;
        float v2 = a2.x * c4.x + a2.y * c4.y + a2.z * c4.z + a2.w * c4.w;
        float v3 = a3.x * c4.x + a3.y * c4.y + a3.z * c4.z + a3.w * c4.w;
        v0 += __shfl_xor(v0, 1); v1 += __shfl_xor(v1, 1);
        v2 += __shfl_xor(v2, 1); v3 += __shfl_xor(v3, 1);
        v0 += __shfl_xor(v0, 2); v1 += __shfl_xor(v1, 2);
        v2 += __shfl_xor(v2, 2); v3 += __shfl_xor(v3, 2);
        v0 += __shfl_xor(v0, 4); v1 += __shfl_xor(v1, 4);
        v2 += __shfl_xor(v2, 4); v3 += __shfl_xor(v3, 4);
        v0 += __shfl_xor(v0, 8); v1 += __shfl_xor(v1, 8);
        v2 += __shfl_xor(v2, 8); v3 += __shfl_xor(v3, 8);
        if (sub == 0) {
            out[eid[j]]      = v0;
            out[eid[j + 4]]  = v1;
            out[eid[j + 8]]  = v2;
            out[eid[j + 12]] = v3;
        }
    }
    // tail
    for (; j < e2; j += 4) {
        int r = srow[j];
        float4 a = *reinterpret_cast<const float4*>(&nr[(long)r * 64 + sub * 4]);
        float v = a.x * c4.x + a.y * c4.y + a.z * c4.z + a.w * c4.w;
        v += __shfl_xor(v, 1);
        v += __shfl_xor(v, 2);
        v += __shfl_xor(v, 4);
        v += __shfl_xor(v, 8);
        if (sub == 0) out[eid[j]] = v;
    }
}

// ==================== fallback path (small ws): atomic scatter ====================
__global__ void k_scatter_simple(const int* __restrict__ row, const int* __restrict__ col,
                                 const float* __restrict__ hs, float* __restrict__ acc, int e) {
    int t = blockIdx.x * blockDim.x + threadIdx.x;
    int lane = t & 63;
    int eidx = t >> 6;
    if (eidx >= e) return;
    int r = row[eidx], c = col[eidx];
    atomicAdd(&acc[(long)c * 64 + lane], hs[(long)r * 64 + lane]);
}
__global__ void k_epilogue2(float* __restrict__ acc, const float* __restrict__ hs,
                            const float* __restrict__ dinv, const float* __restrict__ b, int n) {
    int i = blockIdx.x * blockDim.x + threadIdx.x;
    if (i >= n * 64) return;
    int node = i >> 6, ch = i & 63;
    acc[i] = fmaxf(dinv[node] * (acc[i] + hs[i]) + b[ch], 0.0f);
}
__global__ void k_edge_scores_orig(const int* __restrict__ row, const int* __restrict__ col,
                                   const float* __restrict__ nr, float* __restrict__ out, int e) {
    int t = blockIdx.x * blockDim.x + threadIdx.x;
    int sub = t & 15;
    int eidx = t >> 4;
    if (eidx >= e) return;
    int r = row[eidx], c = col[eidx];
    float4 a  = *reinterpret_cast<const float4*>(&nr[(long)r * 64 + sub * 4]);
    float4 bb = *reinterpret_cast<const float4*>(&nr[(long)c * 64 + sub * 4]);
    float s = a.x * bb.x + a.y * bb.y + a.z * bb.z + a.w * bb.w;
    s += __shfl_xor(s, 1);
    s += __shfl_xor(s, 2);
    s += __shfl_xor(s, 4);
    s += __shfl_xor(s, 8);
    if (sub == 0) out[eidx] = s;
}

extern "C" void kernel_launch(void* const* d_in, const int* in_sizes, int n_in,
                              void* d_out, int out_size, void* d_ws, size_t ws_size,
                              hipStream_t stream) {
    const float* x   = (const float*)d_in[0];
    const int*   ei  = (const int*)d_in[1];
    const float* W1  = (const float*)d_in[2];
    const float* b1  = (const float*)d_in[3];
    const float* W2  = (const float*)d_in[4];
    const float* b2  = (const float*)d_in[5];
    const float* Wd1 = (const float*)d_in[6];
    const float* bd1 = (const float*)d_in[7];
    const float* Wd2 = (const float*)d_in[8];
    const float* bd2 = (const float*)d_in[9];

    const int N = in_sizes[0] / 128;
    const int E = in_sizes[1] / 2;
    const int* row = ei;
    const int* col = ei + E;
    const int n64 = N * 64;
    const int B = (N + 511) >> 9;              // buckets of 512 nodes
    const int nchunks = (E + CH - 1) / CH;     // chunks of 16384 edges

    // d_out layout: recon_x [N*128] | edge_scores [E] | node_repr [N*64]
    float* recon_out  = (float*)d_out;
    float* escore_out = recon_out + (long)N * 128;
    float* nr_out     = escore_out + E;

    // workspace layout
    float* dinv = (float*)d_ws;                 // N
    float* buf1 = dinv + N;                     // N*64 floats (aliased: int2 ebuck[E])
    float* buf2 = buf1 + (long)N * 64;          // N*64
    int* startp = (int*)(buf2 + (long)N * 64);  // N+1
    int* srow   = startp + N + 1;               // E
    int* seid   = srow + E;                     // E
    int* hist   = seid + E;                     // B*nchunks
    int2* ebuck = (int2*)buf1;                  // E int2 (fits: E*2 <= N*64, guarded)

    size_t need_full = sizeof(float) * ((size_t)N + 2uL * n64)
                     + sizeof(int) * ((size_t)N + 1 + 2uL * E + (size_t)B * nchunks);
    bool csr_ok = (ws_size >= need_full) && (E < (1 << 22)) && ((long)E * 2 <= (long)n64)
                  && (B <= 2048);

    if (csr_ok) {
        // ---------- atomic-free CSR build ----------
        k_hist<<<nchunks, 256, B * sizeof(int), stream>>>(col, hist, E, B, nchunks);
        k_scan_tbl<<<1, 1024, 0, stream>>>(hist, (long)B * nchunks);
        k_part2<<<nchunks, 256, B * sizeof(int), stream>>>(row, col, hist, ebuck, E, B, nchunks);
        k_bucket_csr<<<B, 256, 0, stream>>>(ebuck, hist, nchunks, srow, seid, startp, dinv, N, E, B);

        // layer 1: hs1 = (x@W1)*dinv  (overwrites ebuck region - build is done)
        k_gemm<128, 64, false, false, true><<<(N + 15) / 16, 256, 0, stream>>>(x, W1, nullptr, dinv, buf1, N);
        k_gather_conv<<<(N + 3) / 4, 256, 0, stream>>>(startp, srow, buf1, dinv, b1, buf2, N);
        // layer 2
        k_gemm<64, 64, false, false, true><<<(N + 15) / 16, 256, 0, stream>>>(buf2, W2, nullptr, dinv, buf1, N);
        k_gather_conv<<<(N + 3) / 4, 256, 0, stream>>>(startp, srow, buf1, dinv, b2, nr_out, N);
        // decoder
        k_gemm<64, 64, true, true, false><<<(N + 15) / 16, 256, 0, stream>>>(nr_out, Wd1, bd1, nullptr, buf2, N);
        k_gemm<64, 128, true, false, false><<<(N + 7) / 8, 256, 0, stream>>>(buf2, Wd2, bd2, nullptr, recon_out, N);
        // edge scores
        k_edge_scores_csr<<<(N + 3) / 4, 256, 0, stream>>>(startp, srow, seid, nr_out, escore_out, N);
    } else {
        // ---------- fallback: atomic scatter ----------
        int* cnt = startp;
        k_zero_i<<<(N + 255) / 256, 256, 0, stream>>>(cnt, N);
        k_deg_count<<<(E + 255) / 256, 256, 0, stream>>>(col, cnt, E);
        k_dinv<<<(N + 255) / 256, 256, 0, stream>>>(cnt, dinv, N);
        k_zero_f<<<(n64 + 255) / 256, 256, 0, stream>>>(buf2, n64);
        k_zero_f<<<(n64 + 255) / 256, 256, 0, stream>>>(nr_out, n64);

        k_gemm<128, 64, false, false, true><<<(N + 15) / 16, 256, 0, stream>>>(x, W1, nullptr, dinv, buf1, N);
        k_scatter_simple<<<((long)E * 64 + 255) / 256, 256, 0, stream>>>(row, col, buf1, buf2, E);
        k_epilogue2<<<(n64 + 255) / 256, 256, 0, stream>>>(buf2, buf1, dinv, b1, N);
        k_gemm<64, 64, false, false, true><<<(N + 15) / 16, 256, 0, stream>>>(buf2, W2, nullptr, dinv, buf1, N);
        k_scatter_simple<<<((long)E * 64 + 255) / 256, 256, 0, stream>>>(row, col, buf1, nr_out, E);
        k_epilogue2<<<(n64 + 255) / 256, 256, 0, stream>>>(nr_out, buf1, dinv, b2, N);
        k_gemm<64, 64, true, true, false><<<(N + 15) / 16, 256, 0, stream>>>(nr_out, Wd1, bd1, nullptr, buf2, N);
        k_gemm<64, 128, true, false, false><<<(N + 7) / 8, 256, 0, stream>>>(buf2, Wd2, bd2, nullptr, recon_out, N);
        k_edge_scores_orig<<<((long)E * 16 + 255) / 256, 256, 0, stream>>>(row, col, nr_out, escore_out, E);
    }
}

// Round 12
// 909.460 us; speedup vs baseline: 1.8969x; 1.0324x over previous
//
#include <hip/hip_runtime.h>

// ==================== utility ====================
__global__ void k_zero_i(int* __restrict__ p, int n) {
    int i = blockIdx.x * blockDim.x + threadIdx.x;
    if (i < n) p[i] = 0;
}
__global__ void k_zero_f(float* __restrict__ p, long n) {
    long i = blockIdx.x * (long)blockDim.x + threadIdx.x;
    if (i < n) p[i] = 0.0f;
}

// ==================== atomic-free CSR build ====================
// buckets of 512 nodes: bucket = col >> 9. chunks of 16384 edges.
// hist[bucket * nchunks + chunk] -> exclusive scan -> disjoint write windows.

#define CH 16384

// pass 1: per-chunk LDS histogram (no global atomics)
__global__ void k_hist(const int* __restrict__ col, int* __restrict__ hist,
                       int e, int B, int nchunks) {
    extern __shared__ int lh[];
    for (int i = threadIdx.x; i < B; i += 256) lh[i] = 0;
    __syncthreads();
    const int base = blockIdx.x * CH;
    const int end = min(e, base + CH);
    for (int i = base + threadIdx.x; i < end; i += 256)
        atomicAdd(&lh[col[i] >> 9], 1);
    __syncthreads();
    for (int b = threadIdx.x; b < B; b += 256)
        hist[(long)b * nchunks + blockIdx.x] = lh[b];
}

// pass 2: single-block exclusive scan of the whole (bucket-major) table, in place
__global__ void k_scan_tbl(int* __restrict__ hist, long T) {
    __shared__ int ws[1024];
    const int tid = threadIdx.x;
    const long per = (T + 1023) >> 10;
    const long s = tid * per;
    const long e2 = min(T, s + per);
    int sum = 0;
    for (long i = s; i < e2; ++i) sum += hist[i];
    ws[tid] = sum;
    __syncthreads();
    for (int off = 1; off < 1024; off <<= 1) {
        int add = (tid >= off) ? ws[tid - off] : 0;
        __syncthreads();
        ws[tid] += add;
        __syncthreads();
    }
    int run = ws[tid] - sum;   // exclusive prefix of this thread's range
    for (long i = s; i < e2; ++i) { int t = hist[i]; hist[i] = run; run += t; }
}

// pass 3: re-read chunk, rank via LDS cursors, ONE write per edge into a
// private (bucket,chunk) window. No global atomics, no cross-block contention.
__global__ void k_part2(const int* __restrict__ row, const int* __restrict__ col,
                        const int* __restrict__ hist, int2* __restrict__ eb,
                        int e, int B, int nchunks) {
    extern __shared__ int cur[];
    const int bId = blockIdx.x;
    for (int b = threadIdx.x; b < B; b += 256)
        cur[b] = hist[(long)b * nchunks + bId];
    __syncthreads();
    const int base = bId * CH;
    const int end = min(e, base + CH);
    for (int i = base + threadIdx.x; i < end; i += 256) {
        int c = col[i];
        int p = atomicAdd(&cur[c >> 9], 1);
        eb[p] = make_int2(row[i], ((c & 511) << 22) | i);   // eid < 2^22 (guarded)
    }
}

// pass 4: one block per bucket (512 nodes, edges L2-resident):
// LDS count -> scan -> emit startp/dinv -> scatter srow/seid within window.
__global__ void k_bucket_csr(const int2* __restrict__ eb, const int* __restrict__ hist,
                             int nchunks, int* __restrict__ srow, int* __restrict__ seid,
                             int* __restrict__ startp, float* __restrict__ dinv,
                             int n, int e, int B) {
    __shared__ int scnt[512];
    __shared__ int sex[512];
    const int b = blockIdx.x;
    const int tid = threadIdx.x;
    for (int i = tid; i < 512; i += 256) scnt[i] = 0;
    __syncthreads();
    const int s = hist[(long)b * nchunks];
    const int s1 = (b + 1 < B) ? hist[(long)(b + 1) * nchunks] : e;
    for (int i = s + tid; i < s1; i += 256)
        atomicAdd(&scnt[(eb[i].y >> 22) & 511], 1);
    __syncthreads();
    if (tid < 64) {   // wave 0: scan 512 counts (8 per lane, serial + shuffle)
        int vals[8];
        int tot = 0;
        #pragma unroll
        for (int k = 0; k < 8; ++k) { vals[k] = scnt[tid * 8 + k]; tot += vals[k]; }
        int acc = tot;
        #pragma unroll
        for (int off = 1; off < 64; off <<= 1) {
            int t = __shfl_up(acc, off);
            if (tid >= off) acc += t;
        }
        int excl = acc - tot;
        #pragma unroll
        for (int k = 0; k < 8; ++k) {
            sex[tid * 8 + k] = excl;
            int node = b * 512 + tid * 8 + k;
            if (node < n) {
                startp[node] = s + excl;
                dinv[node] = rsqrtf((float)vals[k] + 1.0f);   // +1 self-loop
            }
            excl += vals[k];
        }
    }
    if (b == 0 && tid == 0) startp[n] = e;
    __syncthreads();
    for (int i = tid; i < 512; i += 256) scnt[i] = sex[i];   // cursors
    __syncthreads();
    for (int i = s + tid; i < s1; i += 256) {
        int2 r = eb[i];
        int cl = (r.y >> 22) & 511;
        int p = atomicAdd(&scnt[cl], 1);
        srow[s + p] = r.x;
        seid[s + p] = r.y & 0x3FFFFF;
    }
}

// ==================== degree / dinv (fallback path only) ====================
__global__ void k_deg_count(const int* __restrict__ col, int* __restrict__ cnt, int e) {
    int i = blockIdx.x * blockDim.x + threadIdx.x;
    if (i < e) atomicAdd(&cnt[col[i]], 1);
}
__global__ void k_dinv(const int* __restrict__ cnt, float* __restrict__ dinv, int n) {
    int i = blockIdx.x * blockDim.x + threadIdx.x;
    if (i < n) dinv[i] = rsqrtf((float)cnt[i] + 1.0f);
}

// ==================== small GEMM: out[n][OUT] = in[n][K] @ W[K][OUT] ====================
// LDS-instruction-optimized: sX rows read as float4 (wave-broadcast, conflict-free),
// sW read stride-1 across lanes (conflict-free). 8 LDS insts / 4 k-steps vs 20 scalar.
template<int K, int OUT, bool BIAS, bool RELU, bool SCALE>
__launch_bounds__(256)
__global__ void k_gemm(const float* __restrict__ in, const float* __restrict__ W,
                       const float* __restrict__ b, const float* __restrict__ scale,
                       float* __restrict__ out, int n) {
    constexpr int NPB = 1024 / OUT;
    constexpr int GS  = 256 / OUT;
    __shared__ float sW[K * OUT];
    __shared__ float sX[NPB][K + 4];   // +4 keeps 16B row alignment

    const int tid  = threadIdx.x;
    const int base = blockIdx.x * NPB;

    for (int i = tid; i < K * OUT; i += 256) sW[i] = W[i];
    for (int i = tid; i < NPB * K; i += 256) {
        int m = i / K, k = i - m * K;
        int node = base + m;
        sX[m][k] = (node < n) ? in[(long)node * K + k] : 0.0f;
    }
    __syncthreads();

    const int ch = tid % OUT;
    const int g  = tid / OUT;

    float acc[4] = {0.f, 0.f, 0.f, 0.f};
    #pragma unroll 4
    for (int k = 0; k < K; k += 4) {
        float w0 = sW[(k + 0) * OUT + ch];
        float w1 = sW[(k + 1) * OUT + ch];
        float w2 = sW[(k + 2) * OUT + ch];
        float w3 = sW[(k + 3) * OUT + ch];
        #pragma unroll
        for (int j = 0; j < 4; ++j) {
            float4 x4 = *reinterpret_cast<const float4*>(&sX[g + j * GS][k]);
            acc[j] += x4.x * w0 + x4.y * w1 + x4.z * w2 + x4.w * w3;
        }
    }

    #pragma unroll
    for (int j = 0; j < 4; ++j) {
        int node = base + g + j * GS;
        if (node < n) {
            float v = acc[j];
            if (BIAS) v += b[ch];
            if (RELU) v = fmaxf(v, 0.0f);
            if (SCALE) v *= scale[node];
            out[(long)node * OUT + ch] = v;
        }
    }
}

// ==================== gather-reduce conv (no atomics) ====================
__global__ void k_gather_conv(const int* __restrict__ start, const int* __restrict__ srow,
                              const float* __restrict__ hs, const float* __restrict__ dinv,
                              const float* __restrict__ b, float* __restrict__ out, int n) {
    int node = blockIdx.x * 4 + (threadIdx.x >> 6);
    if (node >= n) return;
    int lane = threadIdx.x & 63;
    int s = start[node], e2 = start[node + 1];
    float acc = hs[(long)node * 64 + lane];   // self-loop
    for (int base = s; base < e2; base += 64) {
        int rem = e2 - base;
        int m = rem < 64 ? rem : 64;
        int rj = (lane < m) ? srow[base + lane] : 0;
        int j = 0;
        for (; j + 8 <= m; j += 8) {
            int r0 = __shfl(rj, j);
            int r1 = __shfl(rj, j + 1);
            int r2 = __shfl(rj, j + 2);
            int r3 = __shfl(rj, j + 3);
            int r4 = __shfl(rj, j + 4);
            int r5 = __shfl(rj, j + 5);
            int r6 = __shfl(rj, j + 6);
            int r7 = __shfl(rj, j + 7);
            float a0 = hs[(long)r0 * 64 + lane];
            float a1 = hs[(long)r1 * 64 + lane];
            float a2 = hs[(long)r2 * 64 + lane];
            float a3 = hs[(long)r3 * 64 + lane];
            float a4 = hs[(long)r4 * 64 + lane];
            float a5 = hs[(long)r5 * 64 + lane];
            float a6 = hs[(long)r6 * 64 + lane];
            float a7 = hs[(long)r7 * 64 + lane];
            acc += a0; acc += a1; acc += a2; acc += a3;
            acc += a4; acc += a5; acc += a6; acc += a7;
        }
        for (; j < m; ++j) {
            int r = __shfl(rj, j);
            acc += hs[(long)r * 64 + lane];
        }
    }
    out[(long)node * 64 + lane] = fmaxf(acc * dinv[node] + b[lane], 0.0f);
}

// ==================== edge scores via CSR (8-way ILP) ====================
// one node per 64-lane wave; 4 edge-groups x 16 lanes; each group keeps 8
// independent row-gathers in flight before reducing (latency hiding).
__launch_bounds__(256)
__global__ void k_edge_scores_csr(const int* __restrict__ start, const int* __restrict__ srow,
                                  const int* __restrict__ eid, const float* __restrict__ nr,
                                  float* __restrict__ out, int n) {
    int node = blockIdx.x * 4 + (threadIdx.x >> 6);
    if (node >= n) return;
    int lane = threadIdx.x & 63;
    int sub = lane & 15;
    int eg  = lane >> 4;
    float4 c4 = *reinterpret_cast<const float4*>(&nr[(long)node * 64 + sub * 4]);
    int s = start[node], e2 = start[node + 1];
    int j = s + eg;
    // main: 8 edges per group per iteration (32 per wave)
    for (; j + 28 < e2; j += 32) {
        int r0 = srow[j];      int r1 = srow[j + 4];
        int r2 = srow[j + 8];  int r3 = srow[j + 12];
        int r4 = srow[j + 16]; int r5 = srow[j + 20];
        int r6 = srow[j + 24]; int r7 = srow[j + 28];
        float4 a0 = *reinterpret_cast<const float4*>(&nr[(long)r0 * 64 + sub * 4]);
        float4 a1 = *reinterpret_cast<const float4*>(&nr[(long)r1 * 64 + sub * 4]);
        float4 a2 = *reinterpret_cast<const float4*>(&nr[(long)r2 * 64 + sub * 4]);
        float4 a3 = *reinterpret_cast<const float4*>(&nr[(long)r3 * 64 + sub * 4]);
        float4 a4 = *reinterpret_cast<const float4*>(&nr[(long)r4 * 64 + sub * 4]);
        float4 a5 = *reinterpret_cast<const float4*>(&nr[(long)r5 * 64 + sub * 4]);
        float4 a6 = *reinterpret_cast<const float4*>(&nr[(long)r6 * 64 + sub * 4]);
        float4 a7 = *reinterpret_cast<const float4*>(&nr[(long)r7 * 64 + sub * 4]);
        float v0 = a0.x * c4.x + a0.y * c4.y + a0.z * c4.z + a0.w * c4.w;
        float v1 = a1.x * c4.x + a1.y * c4.y + a1.z * c4.z + a1.w * c4.w;
        float v2 = a2.x * c4.x + a2.y * c4.y + a2.z * c4.z + a2.w * c4.w;
        float v3 = a3.x * c4.x + a3.y * c4.y + a3.z * c4.z + a3.w * c4.w;
        float v4 = a4.x * c4.x + a4.y * c4.y + a4.z * c4.z + a4.w * c4.w;
        float v5 = a5.x * c4.x + a5.y * c4.y + a5.z * c4.z + a5.w * c4.w;
        float v6 = a6.x * c4.x + a6.y * c4.y + a6.z * c4.z + a6.w * c4.w;
        float v7 = a7.x * c4.x + a7.y * c4.y + a7.z * c4.z + a7.w * c4.w;
        v0 += __shfl_xor(v0, 1); v1 += __shfl_xor(v1, 1);
        v2 += __shfl_xor(v2, 1); v3 += __shfl_xor(v3, 1);
        v4 += __shfl_xor(v4, 1); v5 += __shfl_xor(v5, 1);
        v6 += __shfl_xor(v6, 1); v7 += __shfl_xor(v7, 1);
        v0 += __shfl_xor(v0, 2); v1 += __shfl_xor(v1, 2);
        v2 += __shfl_xor(v2, 2); v3 += __shfl_xor(v3, 2);
        v4 += __shfl_xor(v4, 2); v5 += __shfl_xor(v5, 2);
        v6 += __shfl_xor(v6, 2); v7 += __shfl_xor(v7, 2);
        v0 += __shfl_xor(v0, 4); v1 += __shfl_xor(v1, 4);
        v2 += __shfl_xor(v2, 4); v3 += __shfl_xor(v3, 4);
        v4 += __shfl_xor(v4, 4); v5 += __shfl_xor(v5, 4);
        v6 += __shfl_xor(v6, 4); v7 += __shfl_xor(v7, 4);
        v0 += __shfl_xor(v0, 8); v1 += __shfl_xor(v1, 8);
        v2 += __shfl_xor(v2, 8); v3 += __shfl_xor(v3, 8);
        v4 += __shfl_xor(v4, 8); v5 += __shfl_xor(v5, 8);
        v6 += __shfl_xor(v6, 8); v7 += __shfl_xor(v7, 8);
        if (sub == 0) {
            out[eid[j]]      = v0; out[eid[j + 4]]  = v1;
            out[eid[j + 8]]  = v2; out[eid[j + 12]] = v3;
            out[eid[j + 16]] = v4; out[eid[j + 20]] = v5;
            out[eid[j + 24]] = v6; out[eid[j + 28]] = v7;
        }
    }
    // mid: 4 edges per group
    for (; j + 12 < e2; j += 16) {
        int r0 = srow[j];
        int r1 = srow[j + 4];
        int r2 = srow[j + 8];
        int r3 = srow[j + 12];
        float4 a0 = *reinterpret_cast<const float4*>(&nr[(long)r0 * 64 + sub * 4]);
        float4 a1 = *reinterpret_cast<const float4*>(&nr[(long)r1 * 64 + sub * 4]);
        float4 a2 = *reinterpret_cast<const float4*>(&nr[(long)r2 * 64 + sub * 4]);
        float4 a3 = *reinterpret_cast<const float4*>(&nr[(long)r3 * 64 + sub * 4]);
        float v0 = a0.x * c4.x + a0.y * c4.y + a0.z * c4.z + a0.w * c4.w;
        float v1 = a1.x * c4.x + a1.y * c4.y + a1.z * c4.z + a1.w * c4.w;
        float v2 = a2.x * c4.x + a2.y * c4.y + a2.z * c4.z + a2.w * c4.w;
        float v3 = a3.x * c4.x + a3.y * c4.y + a3.z * c4.z + a3.w * c4.w;
        v0 += __shfl_xor(v0, 1); v1 += __shfl_xor(v1, 1);
        v2 += __shfl_xor(v2, 1); v3 += __shfl_xor(v3, 1);
        v0 += __shfl_xor(v0, 2); v1 += __shfl_xor(v1, 2);
        v2 += __shfl_xor(v2, 2); v3 += __shfl_xor(v3, 2);
        v0 += __shfl_xor(v0, 4); v1 += __shfl_xor(v1, 4);
        v2 += __shfl_xor(v2, 4); v3 += __shfl_xor(v3, 4);
        v0 += __shfl_xor(v0, 8); v1 += __shfl_xor(v1, 8);
        v2 += __shfl_xor(v2, 8); v3 += __shfl_xor(v3, 8);
        if (sub == 0) {
            out[eid[j]]      = v0;
            out[eid[j + 4]]  = v1;
            out[eid[j + 8]]  = v2;
            out[eid[j + 12]] = v3;
        }
    }
    // tail
    for (; j < e2; j += 4) {
        int r = srow[j];
        float4 a = *reinterpret_cast<const float4*>(&nr[(long)r * 64 + sub * 4]);
        float v = a.x * c4.x + a.y * c4.y + a.z * c4.z + a.w * c4.w;
        v += __shfl_xor(v, 1);
        v += __shfl_xor(v, 2);
        v += __shfl_xor(v, 4);
        v += __shfl_xor(v, 8);
        if (sub == 0) out[eid[j]] = v;
    }
}

// ==================== fallback path (small ws): atomic scatter ====================
__global__ void k_scatter_simple(const int* __restrict__ row, const int* __restrict__ col,
                                 const float* __restrict__ hs, float* __restrict__ acc, int e) {
    int t = blockIdx.x * blockDim.x + threadIdx.x;
    int lane = t & 63;
    int eidx = t >> 6;
    if (eidx >= e) return;
    int r = row[eidx], c = col[eidx];
    atomicAdd(&acc[(long)c * 64 + lane], hs[(long)r * 64 + lane]);
}
__global__ void k_epilogue2(float* __restrict__ acc, const float* __restrict__ hs,
                            const float* __restrict__ dinv, const float* __restrict__ b, int n) {
    int i = blockIdx.x * blockDim.x + threadIdx.x;
    if (i >= n * 64) return;
    int node = i >> 6, ch = i & 63;
    acc[i] = fmaxf(dinv[node] * (acc[i] + hs[i]) + b[ch], 0.0f);
}
__global__ void k_edge_scores_orig(const int* __restrict__ row, const int* __restrict__ col,
                                   const float* __restrict__ nr, float* __restrict__ out, int e) {
    int t = blockIdx.x * blockDim.x + threadIdx.x;
    int sub = t & 15;
    int eidx = t >> 4;
    if (eidx >= e) return;
    int r = row[eidx], c = col[eidx];
    float4 a  = *reinterpret_cast<const float4*>(&nr[(long)r * 64 + sub * 4]);
    float4 bb = *reinterpret_cast<const float4*>(&nr[(long)c * 64 + sub * 4]);
    float s = a.x * bb.x + a.y * bb.y + a.z * bb.z + a.w * bb.w;
    s += __shfl_xor(s, 1);
    s += __shfl_xor(s, 2);
    s += __shfl_xor(s, 4);
    s += __shfl_xor(s, 8);
    if (sub == 0) out[eidx] = s;
}

extern "C" void kernel_launch(void* const* d_in, const int* in_sizes, int n_in,
                              void* d_out, int out_size, void* d_ws, size_t ws_size,
                              hipStream_t stream) {
    const float* x   = (const float*)d_in[0];
    const int*   ei  = (const int*)d_in[1];
    const float* W1  = (const float*)d_in[2];
    const float* b1  = (const float*)d_in[3];
    const float* W2  = (const float*)d_in[4];
    const float* b2  = (const float*)d_in[5];
    const float* Wd1 = (const float*)d_in[6];
    const float* bd1 = (const float*)d_in[7];
    const float* Wd2 = (const float*)d_in[8];
    const float* bd2 = (const float*)d_in[9];

    const int N = in_sizes[0] / 128;
    const int E = in_sizes[1] / 2;
    const int* row = ei;
    const int* col = ei + E;
    const int n64 = N * 64;
    const int B = (N + 511) >> 9;              // buckets of 512 nodes
    const int nchunks = (E + CH - 1) / CH;     // chunks of 16384 edges

    // d_out layout: recon_x [N*128] | edge_scores [E] | node_repr [N*64]
    float* recon_out  = (float*)d_out;
    float* escore_out = recon_out + (long)N * 128;
    float* nr_out     = escore_out + E;

    // workspace layout
    float* dinv = (float*)d_ws;                 // N
    float* buf1 = dinv + N;                     // N*64 floats (aliased: int2 ebuck[E])
    float* buf2 = buf1 + (long)N * 64;          // N*64
    int* startp = (int*)(buf2 + (long)N * 64);  // N+1
    int* srow   = startp + N + 1;               // E
    int* seid   = srow + E;                     // E
    int* hist   = seid + E;                     // B*nchunks
    int2* ebuck = (int2*)buf1;                  // E int2 (fits: E*2 <= N*64, guarded)

    size_t need_full = sizeof(float) * ((size_t)N + 2uL * n64)
                     + sizeof(int) * ((size_t)N + 1 + 2uL * E + (size_t)B * nchunks);
    bool csr_ok = (ws_size >= need_full) && (E < (1 << 22)) && ((long)E * 2 <= (long)n64)
                  && (B <= 2048);

    if (csr_ok) {
        // ---------- atomic-free CSR build ----------
        k_hist<<<nchunks, 256, B * sizeof(int), stream>>>(col, hist, E, B, nchunks);
        k_scan_tbl<<<1, 1024, 0, stream>>>(hist, (long)B * nchunks);
        k_part2<<<nchunks, 256, B * sizeof(int), stream>>>(row, col, hist, ebuck, E, B, nchunks);
        k_bucket_csr<<<B, 256, 0, stream>>>(ebuck, hist, nchunks, srow, seid, startp, dinv, N, E, B);

        // layer 1: hs1 = (x@W1)*dinv  (overwrites ebuck region - build is done)
        k_gemm<128, 64, false, false, true><<<(N + 15) / 16, 256, 0, stream>>>(x, W1, nullptr, dinv, buf1, N);
        k_gather_conv<<<(N + 3) / 4, 256, 0, stream>>>(startp, srow, buf1, dinv, b1, buf2, N);
        // layer 2
        k_gemm<64, 64, false, false, true><<<(N + 15) / 16, 256, 0, stream>>>(buf2, W2, nullptr, dinv, buf1, N);
        k_gather_conv<<<(N + 3) / 4, 256, 0, stream>>>(startp, srow, buf1, dinv, b2, nr_out, N);
        // decoder
        k_gemm<64, 64, true, true, false><<<(N + 15) / 16, 256, 0, stream>>>(nr_out, Wd1, bd1, nullptr, buf2, N);
        k_gemm<64, 128, true, false, false><<<(N + 7) / 8, 256, 0, stream>>>(buf2, Wd2, bd2, nullptr, recon_out, N);
        // edge scores
        k_edge_scores_csr<<<(N + 3) / 4, 256, 0, stream>>>(startp, srow, seid, nr_out, escore_out, N);
    } else {
        // ---------- fallback: atomic scatter ----------
        int* cnt = startp;
        k_zero_i<<<(N + 255) / 256, 256, 0, stream>>>(cnt, N);
        k_deg_count<<<(E + 255) / 256, 256, 0, stream>>>(col, cnt, E);
        k_dinv<<<(N + 255) / 256, 256, 0, stream>>>(cnt, dinv, N);
        k_zero_f<<<(n64 + 255) / 256, 256, 0, stream>>>(buf2, n64);
        k_zero_f<<<(n64 + 255) / 256, 256, 0, stream>>>(nr_out, n64);

        k_gemm<128, 64, false, false, true><<<(N + 15) / 16, 256, 0, stream>>>(x, W1, nullptr, dinv, buf1, N);
        k_scatter_simple<<<((long)E * 64 + 255) / 256, 256, 0, stream>>>(row, col, buf1, buf2, E);
        k_epilogue2<<<(n64 + 255) / 256, 256, 0, stream>>>(buf2, buf1, dinv, b1, N);
        k_gemm<64, 64, false, false, true><<<(N + 15) / 16, 256, 0, stream>>>(buf2, W2, nullptr, dinv, buf1, N);
        k_scatter_simple<<<((long)E * 64 + 255) / 256, 256, 0, stream>>>(row, col, buf1, nr_out, E);
        k_epilogue2<<<(n64 + 255) / 256, 256, 0, stream>>>(nr_out, buf1, dinv, b2, N);
        k_gemm<64, 64, true, true, false><<<(N + 15) / 16, 256, 0, stream>>>(nr_out, Wd1, bd1, nullptr, buf2, N);
        k_gemm<64, 128, true, false, false><<<(N + 7) / 8, 256, 0, stream>>>(buf2, Wd2, bd2, nullptr, recon_out, N);
        k_edge_scores_orig<<<((long)E * 16 + 255) / 256, 256, 0, stream>>>(row, col, nr_out, escore_out, E);
    }
}